// Round 1
// baseline (540.044 us; speedup 1.0000x reference)
//
#include <hip/hip_runtime.h>
#include <math.h>

#define B_   32
#define N_   325
#define L_   12
#define D_   128
#define H_   8
#define DK_  16
#define BN_  (B_*N_)        // 10400
#define ROWS_ (BN_*L_)      // 124800
#define TAB_ 23             // 2*MAX_REL+1
#define BNH_ (BN_*H_)       // 83200
#define OUT_MAIN_ ((size_t)ROWS_ * D_)   // 15,974,400 floats

#define XS_  136            // bf16 row stride for staged X
#define QS2_ 132            // fp32 row stride for sQ/sK/sV (132%32=4 -> spread)
#define RS2_ 20             // fp32 row stride for rel tables (16B-aligned rows)
#define PSP_ 148            // pitch for pS/pS2 [8][148] (148%32=20 -> spread)

typedef short v8s __attribute__((ext_vector_type(8)));
typedef float v4f __attribute__((ext_vector_type(4)));

__device__ __forceinline__ unsigned short f2bf_bits(float f) {
    unsigned int u = __float_as_uint(f);
    unsigned int r = (u + 0x7fffu + ((u >> 16) & 1u)) >> 16;
    return (unsigned short)r;
}

// ---------------------------------------------------------------------------
// prep: weight-norm all 4 matrices -> bf16 weights pre-swizzled into the
// MFMA B-fragment order: ushort offset =
//   ((n>>4)*4 + (k>>5))*512 + ((k>>3)&3)*128 + (n&15)*8 + (k&7)
// extra block zeroes the BN accumulators (ws is poisoned 0xAA each launch)
// ---------------------------------------------------------------------------
__global__ __launch_bounds__(64)
void prep_kernel(const float* __restrict__ wqv, const float* __restrict__ wqg,
                 const float* __restrict__ wkv, const float* __restrict__ wkg,
                 const float* __restrict__ wvv, const float* __restrict__ wvg,
                 const float* __restrict__ fcv, const float* __restrict__ fcg,
                 unsigned short* __restrict__ Wb, float* __restrict__ stats)
{
    const int b = blockIdx.x, t = threadIdx.x;
    if (b == 4*D_) {
        for (int j = t; j < 256; j += 64) stats[j] = 0.f;
        return;
    }
    const int m = b >> 7, o = b & 127;
    const float* v; const float* g;
    if      (m == 0) { v = wqv; g = wqg; }
    else if (m == 1) { v = wkv; g = wkg; }
    else if (m == 2) { v = wvv; g = wvg; }
    else             { v = fcv; g = fcg; }
    float x0 = v[o*D_ + t];
    float x1 = v[o*D_ + t + 64];
    float ss = x0*x0 + x1*x1;
    #pragma unroll
    for (int off = 32; off > 0; off >>= 1) ss += __shfl_down(ss, off, 64);
    ss = __shfl(ss, 0, 64);
    const float scale = g[o] / sqrtf(ss);
    unsigned short* W = Wb + m*(D_*D_);
    {
        int k = t;
        int off = ((o>>4)*4 + (k>>5))*512 + ((k>>3)&3)*128 + (o&15)*8 + (k&7);
        W[off] = f2bf_bits(x0*scale);
        k = t + 64;
        off = ((o>>4)*4 + (k>>5))*512 + ((k>>3)&3)*128 + (o&15)*8 + (k&7);
        W[off] = f2bf_bits(x1*scale);
    }
}

// ---------------------------------------------------------------------------
// attention: one block per (b,n). 256 threads = 4 waves.
// Projection via mfma_f32_16x16x32_bf16 (24 (mat,tile) combos over 4 waves);
// score/softmax/mix/context phases fully v4f-vectorized LDS.
// Also accumulates BN per-channel sum/sumsq (replaces bnreduce kernel).
// ---------------------------------------------------------------------------
__global__ __launch_bounds__(256, 4)
void attn_kernel(const float* __restrict__ xq, const float* __restrict__ xk,
                 const float* __restrict__ xv,
                 const float* __restrict__ relk, const float* __restrict__ relv,
                 const float* __restrict__ w1g, const float* __restrict__ w2g,
                 const unsigned short* __restrict__ Wb,
                 float* __restrict__ outm, float* __restrict__ attn_out,
                 float* __restrict__ stats)
{
    // smem region: staged bf16 X during projection; pS/pS2 afterwards
    __shared__ __align__(16) char smem[3*16*XS_*2];      // 13056 B >= 2*4736 B
    __shared__ __align__(16) float sQ[L_][QS2_];
    __shared__ __align__(16) float sK[L_][QS2_];
    __shared__ __align__(16) float sV[L_][QS2_];
    __shared__ __align__(16) float sRk[TAB_*RS2_];
    __shared__ __align__(16) float sRv[TAB_*RS2_];
    __shared__ float sW1[H_*H_];
    __shared__ float sW2[H_*H_];
    __shared__ float sStats[256];

    unsigned short (*sXb)[16][XS_] =
        reinterpret_cast<unsigned short (*)[16][XS_]>(smem);
    float* pS  = (float*)smem;        // [8][PSP_] scores, later attn-final
    float* pS2 = pS + 8*PSP_;         // [8][PSP_] post-softmax

    const int tid = threadIdx.x;
    const int bn  = blockIdx.x;
    const size_t base = (size_t)bn * (L_*D_);

    // ---- stage inputs -> bf16 LDS (rows 12..15 left garbage: only feed
    //      MFMA A-rows 12..15 whose C-rows are discarded) ----
    {
        const float4* q4 = (const float4*)(xq + base);
        const float4* k4 = (const float4*)(xk + base);
        const float4* v4 = (const float4*)(xv + base);
        for (int idx = tid; idx < 3*384; idx += 256) {   // 1152 float4
            const int mat = idx / 384;
            const int rem = idx - mat*384;
            const int row = rem >> 5;
            const int c4  = (rem & 31) * 4;
            const float4* s4 = (mat == 0) ? q4 : ((mat == 1) ? k4 : v4);
            float4 v = s4[rem];
            ushort4 u;
            u.x = f2bf_bits(v.x); u.y = f2bf_bits(v.y);
            u.z = f2bf_bits(v.z); u.w = f2bf_bits(v.w);
            *(ushort4*)&sXb[mat][row][c4] = u;
        }
        for (int idx = tid; idx < TAB_*DK_; idx += 256) {
            const int r = idx >> 4, c = idx & 15;
            sRk[r*RS2_ + c] = relk[idx];
            sRv[r*RS2_ + c] = relv[idx];
        }
        if (tid < H_*H_) { sW1[tid] = w1g[tid]; sW2[tid] = w2g[tid]; }
        sStats[tid] = 0.f;
    }
    __syncthreads();

    // ---- QKV projection via MFMA: 24 (mat,tile) combos, 6 per wave ----
    {
        const int wave = tid >> 6;
        const int lane = tid & 63;
        const int quad = lane >> 4;
        const int c15  = lane & 15;
        const int token0 = quad*4;
        #pragma unroll
        for (int i = 0; i < 6; ++i) {
            const int cb   = wave*6 + i;     // wave-uniform
            const int mat  = cb >> 3;
            const int tile = cb & 7;
            v8s a[4];
            #pragma unroll
            for (int kk = 0; kk < 4; ++kk)
                a[kk] = *(const v8s*)&sXb[mat][c15][kk*32 + quad*8];
            const v8s* WB = (const v8s*)(Wb + mat*(D_*D_));
            v4f acc = {0.f, 0.f, 0.f, 0.f};
            #pragma unroll
            for (int kk = 0; kk < 4; ++kk) {
                v8s bfrag = WB[(tile*4 + kk)*64 + lane];
                acc = __builtin_amdgcn_mfma_f32_16x16x32_bf16(a[kk], bfrag, acc, 0, 0, 0);
            }
            float (*dst)[QS2_] = (mat == 0) ? sQ : ((mat == 1) ? sK : sV);
            #pragma unroll
            for (int r = 0; r < 4; ++r)
                if (token0 + r < L_)
                    dst[token0 + r][tile*16 + c15] = acc[r];
        }
    }
    __syncthreads();

    // ---- scores: s1+s2 = sum_d Q*(K + relK), scale 0.25; all v4f reads ----
    for (int task = tid; task < H_*L_*L_; task += 256) {
        const int h = task / 144;
        const int r = task - h*144;
        const int q = r / 12;
        const int k = r - q*12;
        const float* Qp = &sQ[q][h*DK_];
        const float* Kp = &sK[k][h*DK_];
        const float* Rp = &sRk[(k - q + 11)*RS2_];
        float s = 0.f;
        #pragma unroll
        for (int d4 = 0; d4 < 4; ++d4) {
            v4f qv = *(const v4f*)(Qp + d4*4);
            v4f kv = *(const v4f*)(Kp + d4*4);
            v4f rv = *(const v4f*)(Rp + d4*4);
            s += qv.x*(kv.x+rv.x);
            s += qv.y*(kv.y+rv.y);
            s += qv.z*(kv.z+rv.z);
            s += qv.w*(kv.w+rv.w);
        }
        pS[h*PSP_ + r] = s * 0.25f;
    }
    __syncthreads();

    // ---- w1 mix -> leaky relu -> softmax over k ----
    if (tid < H_*L_) {
        const int g = tid / 12;
        const int q = tid - g*12;
        float vals[L_];
        float mx = -1e30f;
        #pragma unroll
        for (int k = 0; k < L_; ++k) {
            float a = 0.f;
            #pragma unroll
            for (int h = 0; h < H_; ++h) a += pS[h*PSP_ + q*12 + k] * sW1[h*H_ + g];
            a = (a >= 0.f) ? a : 0.2f*a;
            vals[k] = a;
            mx = fmaxf(mx, a);
        }
        float sum = 0.f;
        #pragma unroll
        for (int k = 0; k < L_; ++k) { vals[k] = expf(vals[k] - mx); sum += vals[k]; }
        const float inv = 1.f / sum;
        #pragma unroll
        for (int k = 0; k < L_; ++k) pS2[g*PSP_ + q*12 + k] = vals[k]*inv;
    }
    __syncthreads();

    // ---- w2 mix; write attn_ret[q, bn*H+g, k]; result -> pS ----
    for (int task = tid; task < H_*L_*L_; task += 256) {
        const int g = task / 144;
        const int r = task - g*144;
        const int q = r / 12;
        const int k = r - q*12;
        float a = 0.f;
        #pragma unroll
        for (int h = 0; h < H_; ++h) a += pS2[h*PSP_ + r] * sW2[h*H_ + g];
        pS[g*PSP_ + r] = a;
        attn_out[(size_t)q*((size_t)BNH_*L_) + ((size_t)bn*H_ + g)*L_ + k] = a;
    }
    __syncthreads();

    // ---- context: sum_k attn * (V + relV); v4f over channels; BN stats ----
    {
        v4f s4  = {0.f, 0.f, 0.f, 0.f};
        v4f s24 = {0.f, 0.f, 0.f, 0.f};
        const int c4 = tid & 31;
        const int c  = c4 * 4;
        const int h  = c4 >> 2;
        const int dd = c & 15;
        for (int task = tid; task < L_*32; task += 256) {  // 384 tasks
            const int q = task >> 5;
            const float* Ap = &pS[h*PSP_ + q*12];
            v4f a0 = *(const v4f*)(Ap);
            v4f a1 = *(const v4f*)(Ap + 4);
            v4f a2 = *(const v4f*)(Ap + 8);
            const float av[12] = {a0.x,a0.y,a0.z,a0.w, a1.x,a1.y,a1.z,a1.w,
                                  a2.x,a2.y,a2.z,a2.w};
            v4f acc = {0.f, 0.f, 0.f, 0.f};
            #pragma unroll
            for (int k = 0; k < L_; ++k) {
                const float a = av[k];
                v4f vv = *(const v4f*)&sV[k][c];
                v4f rv = *(const v4f*)&sRv[(k - q + 11)*RS2_ + dd];
                acc.x += a*(vv.x+rv.x);
                acc.y += a*(vv.y+rv.y);
                acc.z += a*(vv.z+rv.z);
                acc.w += a*(vv.w+rv.w);
            }
            *(v4f*)&outm[((size_t)bn*L_ + q)*D_ + c] = acc;
            s4  += acc;
            s24 += acc*acc;
        }
        // lanes l and l+32 share the same channels -> pairwise reduce, then LDS
        const int lane = tid & 63;
        #pragma unroll
        for (int j = 0; j < 4; ++j) {
            float a = s4[j]  + __shfl_down(s4[j],  32, 64);
            float b = s24[j] + __shfl_down(s24[j], 32, 64);
            if (lane < 32) {
                atomicAdd(&sStats[c + j],       a);
                atomicAdd(&sStats[128 + c + j], b);
            }
        }
    }
    __syncthreads();
    atomicAdd(&stats[tid], sStats[tid]);   // 256 threads -> 256 channels
}

// ---------------------------------------------------------------------------
__global__ __launch_bounds__(128)
void bnfinal_kernel(const float* __restrict__ stats,
                    const float* __restrict__ gamma, const float* __restrict__ beta,
                    float* __restrict__ stats2)
{
    const int c = threadIdx.x;
    const float invn = 1.f / (float)ROWS_;
    float mean = stats[c]*invn;
    float var  = stats[c+128]*invn - mean*mean;
    float sc   = rsqrtf(var + 1e-5f) * gamma[c];
    stats2[c]     = sc;
    stats2[c+128] = beta[c] - mean*sc;
}

// ---------------------------------------------------------------------------
// fc: normalize ctx (in outm) -> bf16 LDS, MFMA vs Wfc, relu+residual in place.
// 16 rows per block, 256 threads = 4 waves; wave w does N-tiles {2w, 2w+1}.
// ---------------------------------------------------------------------------
__global__ __launch_bounds__(256, 4)
void fc_kernel(float* __restrict__ outm, const float* __restrict__ stats2,
               const unsigned short* __restrict__ Wfc,
               const float* __restrict__ resid)
{
    __shared__ float sSS[256];
    __shared__ __align__(16) unsigned short sC[16][XS_];
    const int tid = threadIdx.x;
    const size_t row0 = (size_t)blockIdx.x * 16;

    sSS[tid] = stats2[tid];
    __syncthreads();
    for (int idx = tid; idx < 16*D_/4; idx += 256) {   // 512 float4
        const int r  = idx >> 5;
        const int c4 = (idx & 31) * 4;
        float4 v = *(const float4*)&outm[(row0 + r)*D_ + c4];
        ushort4 u;
        u.x = f2bf_bits(v.x*sSS[c4+0] + sSS[128+c4+0]);
        u.y = f2bf_bits(v.y*sSS[c4+1] + sSS[128+c4+1]);
        u.z = f2bf_bits(v.z*sSS[c4+2] + sSS[128+c4+2]);
        u.w = f2bf_bits(v.w*sSS[c4+3] + sSS[128+c4+3]);
        *(ushort4*)&sC[r][c4] = u;
    }
    __syncthreads();

    const int wave = tid >> 6;
    const int lane = tid & 63;
    const int quad = lane >> 4;
    const int c15  = lane & 15;
    v8s a[4];
    #pragma unroll
    for (int kk = 0; kk < 4; ++kk)
        a[kk] = *(const v8s*)&sC[c15][kk*32 + quad*8];
    const v8s* WB = (const v8s*)Wfc;
    #pragma unroll
    for (int tt = 0; tt < 2; ++tt) {
        const int tile = wave*2 + tt;
        v4f acc = {0.f, 0.f, 0.f, 0.f};
        #pragma unroll
        for (int kk = 0; kk < 4; ++kk) {
            v8s bfrag = WB[(tile*4 + kk)*64 + lane];
            acc = __builtin_amdgcn_mfma_f32_16x16x32_bf16(a[kk], bfrag, acc, 0, 0, 0);
        }
        #pragma unroll
        for (int r = 0; r < 4; ++r) {
            const size_t aidx = (row0 + quad*4 + r)*D_ + tile*16 + c15;
            outm[aidx] = fmaxf(acc[r], 0.f) + resid[aidx];
        }
    }
}

// ---------------------------------------------------------------------------
extern "C" void kernel_launch(void* const* d_in, const int* in_sizes, int n_in,
                              void* d_out, int out_size, void* d_ws, size_t ws_size,
                              hipStream_t stream)
{
    const float* xq   = (const float*)d_in[0];
    const float* xk   = (const float*)d_in[1];
    const float* xv   = (const float*)d_in[2];
    const float* wqv  = (const float*)d_in[3];
    const float* wqg  = (const float*)d_in[4];
    const float* wkv  = (const float*)d_in[5];
    const float* wkg  = (const float*)d_in[6];
    const float* wvv  = (const float*)d_in[7];
    const float* wvg  = (const float*)d_in[8];
    const float* fcv  = (const float*)d_in[9];
    const float* fcg  = (const float*)d_in[10];
    const float* relk = (const float*)d_in[11];
    const float* relv = (const float*)d_in[12];
    const float* w1   = (const float*)d_in[13];
    const float* w2   = (const float*)d_in[14];
    const float* gam  = (const float*)d_in[15];
    const float* bet  = (const float*)d_in[16];

    // ws layout: Wb bf16 swizzled (4*128*128 ushort = 128 KB) | stats | stats2
    unsigned short* Wb = (unsigned short*)d_ws;
    float* stats  = (float*)((char*)d_ws + 4*D_*D_*sizeof(unsigned short));
    float* stats2 = stats + 256;

    float* outm     = (float*)d_out;          // main output; temporarily holds ctx
    float* attn_out = outm + OUT_MAIN_;

    prep_kernel<<<4*D_ + 1, 64, 0, stream>>>(wqv,wqg, wkv,wkg, wvv,wvg, fcv,fcg,
                                             Wb, stats);
    attn_kernel<<<BN_, 256, 0, stream>>>(xq, xk, xv, relk, relv, w1, w2,
                                         Wb, outm, attn_out, stats);
    bnfinal_kernel<<<1, 128, 0, stream>>>(stats, gam, bet, stats2);
    fc_kernel<<<ROWS_/16, 256, 0, stream>>>(outm, stats2, Wb + 3*D_*D_, xv);
}

// Round 3
// 434.834 us; speedup vs baseline: 1.2420x; 1.2420x over previous
//
#include <hip/hip_runtime.h>
#include <math.h>

#define B_   32
#define N_   325
#define L_   12
#define D_   128
#define H_   8
#define DK_  16
#define BN_  (B_*N_)        // 10400
#define ROWS_ (BN_*L_)      // 124800
#define TAB_ 23             // 2*MAX_REL+1
#define BNH_ (BN_*H_)       // 83200
#define OUT_MAIN_ ((size_t)ROWS_ * D_)   // 15,974,400 floats

#define XS_  136            // bf16 row stride for staged X
#define QS2_ 132            // fp32 row stride for sQ/sK/sV (132%32=4 -> spread)
#define RS2_ 20             // fp32 row stride for rel tables (16B-aligned rows)
#define PSP_ 148            // pitch for pS/pS2 [8][148] (148%32=20 -> spread)
#define NCMAX_ 64           // max spread copies for BN stats

typedef short v8s __attribute__((ext_vector_type(8)));
typedef float v4f __attribute__((ext_vector_type(4)));

__device__ __forceinline__ unsigned short f2bf_bits(float f) {
    unsigned int u = __float_as_uint(f);
    unsigned int r = (u + 0x7fffu + ((u >> 16) & 1u)) >> 16;
    return (unsigned short)r;
}

// ---------------------------------------------------------------------------
// prep: weight-norm all 4 matrices -> bf16 weights pre-swizzled into the
// MFMA B-fragment order: ushort offset =
//   ((n>>4)*4 + (k>>5))*512 + ((k>>3)&3)*128 + (n&15)*8 + (k&7)
// blocks >= 512 zero the spread BN accumulators (ws poisoned each launch)
// ---------------------------------------------------------------------------
__global__ __launch_bounds__(64)
void prep_kernel(const float* __restrict__ wqv, const float* __restrict__ wqg,
                 const float* __restrict__ wkv, const float* __restrict__ wkg,
                 const float* __restrict__ wvv, const float* __restrict__ wvg,
                 const float* __restrict__ fcv, const float* __restrict__ fcg,
                 unsigned short* __restrict__ Wb, float* __restrict__ stats,
                 int statn)
{
    const int b = blockIdx.x, t = threadIdx.x;
    if (b >= 4*D_) {
        // 16 blocks zero statn floats (up to 1024 each)
        const int b0 = (b - 4*D_) * 1024;
        #pragma unroll
        for (int j = 0; j < 16; ++j) {
            const int o = b0 + j*64 + t;
            if (o < statn) stats[o] = 0.f;
        }
        return;
    }
    const int m = b >> 7, o = b & 127;
    const float* v; const float* g;
    if      (m == 0) { v = wqv; g = wqg; }
    else if (m == 1) { v = wkv; g = wkg; }
    else if (m == 2) { v = wvv; g = wvg; }
    else             { v = fcv; g = fcg; }
    float x0 = v[o*D_ + t];
    float x1 = v[o*D_ + t + 64];
    float ss = x0*x0 + x1*x1;
    #pragma unroll
    for (int off = 32; off > 0; off >>= 1) ss += __shfl_down(ss, off, 64);
    ss = __shfl(ss, 0, 64);
    const float scale = g[o] / sqrtf(ss);
    unsigned short* W = Wb + m*(D_*D_);
    {
        int k = t;
        int off = ((o>>4)*4 + (k>>5))*512 + ((k>>3)&3)*128 + (o&15)*8 + (k&7);
        W[off] = f2bf_bits(x0*scale);
        k = t + 64;
        off = ((o>>4)*4 + (k>>5))*512 + ((k>>3)&3)*128 + (o&15)*8 + (k&7);
        W[off] = f2bf_bits(x1*scale);
    }
}

// ---------------------------------------------------------------------------
// attention: one block per (b,n). 256 threads = 4 waves.
// Projection via mfma_f32_16x16x32_bf16 (24 (mat,tile) combos over 4 waves);
// score/softmax/mix/context phases v4f-vectorized LDS.
// BN partial sums -> stats copy (bn & statmask): no atomic contention.
// ---------------------------------------------------------------------------
__global__ __launch_bounds__(256, 4)
void attn_kernel(const float* __restrict__ xq, const float* __restrict__ xk,
                 const float* __restrict__ xv,
                 const float* __restrict__ relk, const float* __restrict__ relv,
                 const float* __restrict__ w1g, const float* __restrict__ w2g,
                 const unsigned short* __restrict__ Wb,
                 float* __restrict__ outm, float* __restrict__ attn_out,
                 float* __restrict__ stats, int statmask)
{
    // smem region: staged bf16 X during projection; pS/pS2 afterwards
    __shared__ __align__(16) char smem[3*16*XS_*2];      // 13056 B >= 2*4736 B
    __shared__ __align__(16) float sQ[L_][QS2_];
    __shared__ __align__(16) float sK[L_][QS2_];
    __shared__ __align__(16) float sV[L_][QS2_];
    __shared__ __align__(16) float sRk[TAB_*RS2_];
    __shared__ __align__(16) float sRv[TAB_*RS2_];
    __shared__ float sW1[H_*H_];
    __shared__ float sW2[H_*H_];
    __shared__ float sStats[256];

    unsigned short (*sXb)[16][XS_] =
        reinterpret_cast<unsigned short (*)[16][XS_]>(smem);
    float* pS  = (float*)smem;        // [8][PSP_] scores, later attn-final
    float* pS2 = pS + 8*PSP_;         // [8][PSP_] post-softmax

    const int tid = threadIdx.x;
    const int bn  = blockIdx.x;
    const size_t base = (size_t)bn * (L_*D_);

    // ---- stage inputs -> bf16 LDS (rows 12..15 left garbage: only feed
    //      MFMA A-rows 12..15 whose C-rows are discarded) ----
    {
        const float4* q4 = (const float4*)(xq + base);
        const float4* k4 = (const float4*)(xk + base);
        const float4* v4 = (const float4*)(xv + base);
        for (int idx = tid; idx < 3*384; idx += 256) {   // 1152 float4
            const int mat = idx / 384;
            const int rem = idx - mat*384;
            const int row = rem >> 5;
            const int c4  = (rem & 31) * 4;
            const float4* s4 = (mat == 0) ? q4 : ((mat == 1) ? k4 : v4);
            float4 v = s4[rem];
            ushort4 u;
            u.x = f2bf_bits(v.x); u.y = f2bf_bits(v.y);
            u.z = f2bf_bits(v.z); u.w = f2bf_bits(v.w);
            *(ushort4*)&sXb[mat][row][c4] = u;
        }
        for (int idx = tid; idx < TAB_*DK_; idx += 256) {
            const int r = idx >> 4, c = idx & 15;
            sRk[r*RS2_ + c] = relk[idx];
            sRv[r*RS2_ + c] = relv[idx];
        }
        if (tid < H_*H_) { sW1[tid] = w1g[tid]; sW2[tid] = w2g[tid]; }
        sStats[tid] = 0.f;
    }
    __syncthreads();

    // ---- QKV projection via MFMA: 24 (mat,tile) combos, 6 per wave ----
    {
        const int wave = tid >> 6;
        const int lane = tid & 63;
        const int quad = lane >> 4;
        const int c15  = lane & 15;
        const int token0 = quad*4;
        #pragma unroll
        for (int i = 0; i < 6; ++i) {
            const int cb   = wave*6 + i;     // wave-uniform
            const int mat  = cb >> 3;
            const int tile = cb & 7;
            v8s a[4];
            #pragma unroll
            for (int kk = 0; kk < 4; ++kk)
                a[kk] = *(const v8s*)&sXb[mat][c15][kk*32 + quad*8];
            const v8s* WB = (const v8s*)(Wb + mat*(D_*D_));
            v4f acc = {0.f, 0.f, 0.f, 0.f};
            #pragma unroll
            for (int kk = 0; kk < 4; ++kk) {
                v8s bfrag = WB[(tile*4 + kk)*64 + lane];
                acc = __builtin_amdgcn_mfma_f32_16x16x32_bf16(a[kk], bfrag, acc, 0, 0, 0);
            }
            float (*dst)[QS2_] = (mat == 0) ? sQ : ((mat == 1) ? sK : sV);
            #pragma unroll
            for (int r = 0; r < 4; ++r)
                if (token0 + r < L_)
                    dst[token0 + r][tile*16 + c15] = acc[r];
        }
    }
    __syncthreads();

    // ---- scores: s1+s2 = sum_d Q*(K + relK), scale 0.25; all v4f reads ----
    for (int task = tid; task < H_*L_*L_; task += 256) {
        const int h = task / 144;
        const int r = task - h*144;
        const int q = r / 12;
        const int k = r - q*12;
        const float* Qp = &sQ[q][h*DK_];
        const float* Kp = &sK[k][h*DK_];
        const float* Rp = &sRk[(k - q + 11)*RS2_];
        float s = 0.f;
        #pragma unroll
        for (int d4 = 0; d4 < 4; ++d4) {
            v4f qv = *(const v4f*)(Qp + d4*4);
            v4f kv = *(const v4f*)(Kp + d4*4);
            v4f rv = *(const v4f*)(Rp + d4*4);
            s += qv.x*(kv.x+rv.x);
            s += qv.y*(kv.y+rv.y);
            s += qv.z*(kv.z+rv.z);
            s += qv.w*(kv.w+rv.w);
        }
        pS[h*PSP_ + r] = s * 0.25f;
    }
    __syncthreads();

    // ---- w1 mix -> leaky relu -> softmax over k ----
    if (tid < H_*L_) {
        const int g = tid / 12;
        const int q = tid - g*12;
        float vals[L_];
        float mx = -1e30f;
        #pragma unroll
        for (int k = 0; k < L_; ++k) {
            float a = 0.f;
            #pragma unroll
            for (int h = 0; h < H_; ++h) a += pS[h*PSP_ + q*12 + k] * sW1[h*H_ + g];
            a = (a >= 0.f) ? a : 0.2f*a;
            vals[k] = a;
            mx = fmaxf(mx, a);
        }
        float sum = 0.f;
        #pragma unroll
        for (int k = 0; k < L_; ++k) { vals[k] = expf(vals[k] - mx); sum += vals[k]; }
        const float inv = 1.f / sum;
        #pragma unroll
        for (int k = 0; k < L_; ++k) pS2[g*PSP_ + q*12 + k] = vals[k]*inv;
    }
    __syncthreads();

    // ---- w2 mix; write attn_ret[q, bn*H+g, k]; result -> pS ----
    for (int task = tid; task < H_*L_*L_; task += 256) {
        const int g = task / 144;
        const int r = task - g*144;
        const int q = r / 12;
        const int k = r - q*12;
        float a = 0.f;
        #pragma unroll
        for (int h = 0; h < H_; ++h) a += pS2[h*PSP_ + r] * sW2[h*H_ + g];
        pS[g*PSP_ + r] = a;
        attn_out[(size_t)q*((size_t)BNH_*L_) + ((size_t)bn*H_ + g)*L_ + k] = a;
    }
    __syncthreads();

    // ---- context: sum_k attn * (V + relV); v4f over channels; BN stats ----
    {
        v4f s4  = {0.f, 0.f, 0.f, 0.f};
        v4f s24 = {0.f, 0.f, 0.f, 0.f};
        const int c4 = tid & 31;
        const int c  = c4 * 4;
        const int h  = c4 >> 2;
        const int dd = c & 15;
        for (int task = tid; task < L_*32; task += 256) {  // 384 tasks
            const int q = task >> 5;
            const float* Ap = &pS[h*PSP_ + q*12];
            v4f a0 = *(const v4f*)(Ap);
            v4f a1 = *(const v4f*)(Ap + 4);
            v4f a2 = *(const v4f*)(Ap + 8);
            const float av[12] = {a0.x,a0.y,a0.z,a0.w, a1.x,a1.y,a1.z,a1.w,
                                  a2.x,a2.y,a2.z,a2.w};
            v4f acc = {0.f, 0.f, 0.f, 0.f};
            #pragma unroll
            for (int k = 0; k < L_; ++k) {
                const float a = av[k];
                v4f vv = *(const v4f*)&sV[k][c];
                v4f rv = *(const v4f*)&sRv[(k - q + 11)*RS2_ + dd];
                acc.x += a*(vv.x+rv.x);
                acc.y += a*(vv.y+rv.y);
                acc.z += a*(vv.z+rv.z);
                acc.w += a*(vv.w+rv.w);
            }
            *(v4f*)&outm[((size_t)bn*L_ + q)*D_ + c] = acc;
            s4  += acc;
            s24 += acc*acc;
        }
        // lanes l and l+32 share the same channels -> pairwise reduce, then LDS
        const int lane = tid & 63;
        #pragma unroll
        for (int j = 0; j < 4; ++j) {
            float a = s4[j]  + __shfl_down(s4[j],  32, 64);
            float b = s24[j] + __shfl_down(s24[j], 32, 64);
            if (lane < 32) {
                atomicAdd(&sStats[c + j],       a);
                atomicAdd(&sStats[128 + c + j], b);
            }
        }
    }
    __syncthreads();
    // spread copy (bn & statmask): ~162 blocks/address at 64 copies
    atomicAdd(&stats[(bn & statmask)*256 + tid], sStats[tid]);
}

// ---------------------------------------------------------------------------
__global__ __launch_bounds__(128)
void bnfinal_kernel(const float* __restrict__ stats,
                    const float* __restrict__ gamma, const float* __restrict__ beta,
                    float* __restrict__ stats2, int nc)
{
    const int c = threadIdx.x;
    float s = 0.f, s2 = 0.f;
    for (int j = 0; j < nc; ++j) {
        s  += stats[j*256 + c];
        s2 += stats[j*256 + c + 128];
    }
    const float invn = 1.f / (float)ROWS_;
    float mean = s*invn;
    float var  = s2*invn - mean*mean;
    float sc   = rsqrtf(var + 1e-5f) * gamma[c];
    stats2[c]     = sc;
    stats2[c+128] = beta[c] - mean*sc;
}

// ---------------------------------------------------------------------------
// fc: normalize ctx (in outm) -> bf16 LDS, MFMA vs Wfc, relu+residual in place.
// 16 rows per block, 256 threads = 4 waves; wave w does N-tiles {2w, 2w+1}.
// ---------------------------------------------------------------------------
__global__ __launch_bounds__(256, 4)
void fc_kernel(float* __restrict__ outm, const float* __restrict__ stats2,
               const unsigned short* __restrict__ Wfc,
               const float* __restrict__ resid)
{
    __shared__ float sSS[256];
    __shared__ __align__(16) unsigned short sC[16][XS_];
    const int tid = threadIdx.x;
    const size_t row0 = (size_t)blockIdx.x * 16;

    sSS[tid] = stats2[tid];
    __syncthreads();
    for (int idx = tid; idx < 16*D_/4; idx += 256) {   // 512 float4
        const int r  = idx >> 5;
        const int c4 = (idx & 31) * 4;
        float4 v = *(const float4*)&outm[(row0 + r)*D_ + c4];
        ushort4 u;
        u.x = f2bf_bits(v.x*sSS[c4+0] + sSS[128+c4+0]);
        u.y = f2bf_bits(v.y*sSS[c4+1] + sSS[128+c4+1]);
        u.z = f2bf_bits(v.z*sSS[c4+2] + sSS[128+c4+2]);
        u.w = f2bf_bits(v.w*sSS[c4+3] + sSS[128+c4+3]);
        *(ushort4*)&sC[r][c4] = u;
    }
    __syncthreads();

    const int wave = tid >> 6;
    const int lane = tid & 63;
    const int quad = lane >> 4;
    const int c15  = lane & 15;
    v8s a[4];
    #pragma unroll
    for (int kk = 0; kk < 4; ++kk)
        a[kk] = *(const v8s*)&sC[c15][kk*32 + quad*8];
    const v8s* WB = (const v8s*)Wfc;
    #pragma unroll
    for (int tt = 0; tt < 2; ++tt) {
        const int tile = wave*2 + tt;
        v4f acc = {0.f, 0.f, 0.f, 0.f};
        #pragma unroll
        for (int kk = 0; kk < 4; ++kk) {
            v8s bfrag = WB[(tile*4 + kk)*64 + lane];
            acc = __builtin_amdgcn_mfma_f32_16x16x32_bf16(a[kk], bfrag, acc, 0, 0, 0);
        }
        #pragma unroll
        for (int r = 0; r < 4; ++r) {
            const size_t aidx = (row0 + quad*4 + r)*D_ + tile*16 + c15;
            outm[aidx] = fmaxf(acc[r], 0.f) + resid[aidx];
        }
    }
}

// ---------------------------------------------------------------------------
extern "C" void kernel_launch(void* const* d_in, const int* in_sizes, int n_in,
                              void* d_out, int out_size, void* d_ws, size_t ws_size,
                              hipStream_t stream)
{
    const float* xq   = (const float*)d_in[0];
    const float* xk   = (const float*)d_in[1];
    const float* xv   = (const float*)d_in[2];
    const float* wqv  = (const float*)d_in[3];
    const float* wqg  = (const float*)d_in[4];
    const float* wkv  = (const float*)d_in[5];
    const float* wkg  = (const float*)d_in[6];
    const float* wvv  = (const float*)d_in[7];
    const float* wvg  = (const float*)d_in[8];
    const float* fcv  = (const float*)d_in[9];
    const float* fcg  = (const float*)d_in[10];
    const float* relk = (const float*)d_in[11];
    const float* relv = (const float*)d_in[12];
    const float* w1   = (const float*)d_in[13];
    const float* w2   = (const float*)d_in[14];
    const float* gam  = (const float*)d_in[15];
    const float* bet  = (const float*)d_in[16];

    // ws layout: Wb bf16 swizzled (128 KB) | stats spread (nc*1 KB) | stats2 (1 KB)
    const size_t wboff = 4*D_*D_*sizeof(unsigned short);   // 131072
    unsigned short* Wb = (unsigned short*)d_ws;

    // nc = largest power-of-two #copies that fits in the workspace, <= 64, >= 1
    // (known-good prior footprint was wboff + 2 KB, so nc >= 1 always fits)
    long avail = (long)((ws_size - wboff) / sizeof(float)) - 256;  // minus stats2
    int nc = 1;
    while (nc < NCMAX_ && (long)(nc*2)*256 <= avail) nc *= 2;

    float* stats  = (float*)((char*)d_ws + wboff);
    float* stats2 = stats + (size_t)nc*256;

    float* outm     = (float*)d_out;          // main output; temporarily holds ctx
    float* attn_out = outm + OUT_MAIN_;

    prep_kernel<<<4*D_ + 16, 64, 0, stream>>>(wqv,wqg, wkv,wkg, wvv,wvg, fcv,fcg,
                                              Wb, stats, nc*256);
    attn_kernel<<<BN_, 256, 0, stream>>>(xq, xk, xv, relk, relv, w1, w2,
                                         Wb, outm, attn_out, stats, nc - 1);
    bnfinal_kernel<<<1, 128, 0, stream>>>(stats, gam, bet, stats2, nc);
    fc_kernel<<<ROWS_/16, 256, 0, stream>>>(outm, stats2, Wb + 3*D_*D_, xv);
}